// Round 1
// baseline (533.691 us; speedup 1.0000x reference)
//
#include <hip/hip_runtime.h>

// CropRandomizer.forward_in with pos_enc=True, specialized to:
//   B=64, C=3, H=W=240, NUM_CROPS=8, CROP=216x216, Cp=5
// Output: [512, 5, 216, 216] fp32 = 477.8 MB. Memory-bound on the write side.

#define CROP_HW   216
#define N_CROPS   8
#define IMG_B     64
#define IMG_C     3
#define IMG_H     240
#define IMG_W     240
#define CP        5

// Per-plane float4 counts (216*216/4 = 11664), per-crop (5*11664 = 58320)
#define ROW4      (CROP_HW / 4)          // 54 float4 per row
#define PLANE4    (CROP_HW * ROW4)       // 11664
#define CROP4     (CP * PLANE4)          // 58320

__global__ __launch_bounds__(256) void crop_pos_kernel(
    const float* __restrict__ images,
    const int*   __restrict__ ch,
    const int*   __restrict__ cw,
    float4*      __restrict__ out,
    unsigned int total4)
{
    const float inv = 1.0f / 240.0f;
    unsigned int stride = gridDim.x * blockDim.x;
    for (unsigned int idx = blockIdx.x * blockDim.x + threadIdx.x;
         idx < total4; idx += stride) {

        // Decompose idx -> (n, c, i, j4). Constant divisors -> magic multiplies.
        unsigned int n    = idx / CROP4;
        unsigned int rem  = idx - n * CROP4;
        unsigned int c    = rem / PLANE4;
        unsigned int rem2 = rem - c * PLANE4;
        unsigned int i    = rem2 / ROW4;
        unsigned int j    = (rem2 - i * ROW4) * 4;

        unsigned int b  = n >> 3;          // image index
        unsigned int cr = n & 7;           // crop index within image
        int h0 = ch[b * N_CROPS + cr];
        int w0 = cw[b * N_CROPS + cr];

        float4 v;
        if (c < IMG_C) {
            const float* src = images
                + (((b * IMG_C + c) * IMG_H) + (unsigned)(h0 + (int)i)) * IMG_W
                + (unsigned)(w0 + (int)j);
            v.x = src[0]; v.y = src[1]; v.z = src[2]; v.w = src[3];
        } else if (c == 3) {
            // yy channel: (h0 + i) / H, constant across the row
            float val = (float)(h0 + (int)i) * inv;
            v.x = val; v.y = val; v.z = val; v.w = val;
        } else {
            // xx channel: (w0 + j + t) / W
            float base = (float)(w0 + (int)j) * inv;
            v.x = base;
            v.y = base + inv;
            v.z = base + 2.0f * inv;
            v.w = base + 3.0f * inv;
        }
        out[idx] = v;
    }
}

extern "C" void kernel_launch(void* const* d_in, const int* in_sizes, int n_in,
                              void* d_out, int out_size, void* d_ws, size_t ws_size,
                              hipStream_t stream) {
    const float* images = (const float*)d_in[0];
    const int*   ch     = (const int*)d_in[1];
    const int*   cw     = (const int*)d_in[2];
    float4*      out    = (float4*)d_out;

    unsigned int total4 = (unsigned int)(out_size / 4);   // 29,859,840
    dim3 block(256);
    dim3 grid(2048);                                      // grid-stride, ~57 iters/thread
    crop_pos_kernel<<<grid, block, 0, stream>>>(images, ch, cw, out, total4);
}